// Round 1
// baseline (223.487 us; speedup 1.0000x reference)
//
#include <hip/hip_runtime.h>
#include <hip/hip_bf16.h>

typedef short v8s __attribute__((ext_vector_type(8)));
typedef short v4s __attribute__((ext_vector_type(4)));
typedef float v4f __attribute__((ext_vector_type(4)));
typedef unsigned short ushort_t;

#define BM 128
#define BN 128
#define BK 64

__device__ __forceinline__ unsigned short f2bf(float f) {
    unsigned int u = __float_as_uint(f);
    u = (u + 0x7FFFu + ((u >> 16) & 1u)) >> 16;   // RNE
    return (unsigned short)u;
}

__device__ __forceinline__ void load_lds16(const void* g, void* l) {
    __builtin_amdgcn_global_load_lds((const __attribute__((address_space(1))) void*)g,
                                     (__attribute__((address_space(3))) void*)l,
                                     16, 0, 0);
}

// ---------------------------------------------------------------------------
// fp32 -> bf16 elementwise convert (vectorized float4 -> 4x bf16)
__global__ __launch_bounds__(256) void cvt_kernel(const float4* __restrict__ in,
                                                  ushort_t* __restrict__ out, int n4) {
    int i = blockIdx.x * 256 + threadIdx.x;
    int stride = gridDim.x * 256;
    for (; i < n4; i += stride) {
        float4 v = in[i];
        v4s p;
        p[0] = (short)f2bf(v.x); p[1] = (short)f2bf(v.y);
        p[2] = (short)f2bf(v.z); p[3] = (short)f2bf(v.w);
        *(v4s*)(out + (size_t)i * 4) = p;
    }
}

// ---------------------------------------------------------------------------
// W (K x N, fp32, row-major) -> Wt (N x K, bf16) for the 3 projection weights
__global__ void transpose_w(const float* __restrict__ W0, const float* __restrict__ W1,
                            const float* __restrict__ W2, ushort_t* __restrict__ WtAll) {
    const float* W = (blockIdx.z == 0) ? W0 : (blockIdx.z == 1 ? W1 : W2);
    ushort_t* out = WtAll + (size_t)blockIdx.z * 1024 * 1024;
    __shared__ float tile[32][33];
    int n0 = blockIdx.x * 32, k0 = blockIdx.y * 32;
    int tx = threadIdx.x, ty = threadIdx.y;       // block (32, 8)
    #pragma unroll
    for (int i = 0; i < 32; i += 8)
        tile[ty + i][tx] = W[(size_t)(k0 + ty + i) * 1024 + n0 + tx];
    __syncthreads();
    #pragma unroll
    for (int i = 0; i < 32; i += 8)
        out[(size_t)(n0 + ty + i) * 1024 + k0 + tx] = f2bf(tile[tx][ty + i]);
}

// ---------------------------------------------------------------------------
// 128x128 tile GEMM, C = A * Bt^T   (A: MxK row-major, Bt: NxK row-major)
// MODE 0: bf16 out row-major, + bias, * scale           (Q, K projections)
// MODE 1: bf16 out transposed per-batch [e][s], + bias   (V^T)
// MODE 2: fp32 out row-major, skip blocks above diagonal (scores), batched
// MODE 3: fp32 out row-major, K limited to (by+1)*BM     (PV), batched
template <int MODE>
__global__ __launch_bounds__(256)
void gemm_bt(const ushort_t* __restrict__ A, int lda, long long strideA,
             const ushort_t* __restrict__ Bt, int ldb, long long strideB,
             const float* __restrict__ bias,
             void* __restrict__ Cv, int ldc, long long strideC,
             int K, float scale)
{
    const int bx = blockIdx.x, by = blockIdx.y, bz = blockIdx.z;
    if constexpr (MODE == 2) { if (bx > by) return; }

    const int tid = threadIdx.x;
    const int lane = tid & 63, wid = tid >> 6;
    const int wr = wid >> 1, wc = wid & 1;

    A  += (size_t)bz * strideA;
    Bt += (size_t)bz * strideB;

    __shared__ ushort_t As[BM * BK];
    __shared__ ushort_t Bs[BN * BK];

    const int brow = by * BM, bcol = bx * BN;

    int kEnd = K;
    if constexpr (MODE == 3) { int lim = (by + 1) * BM; kEnd = lim < K ? lim : K; }

    v4f acc[4][4];
    #pragma unroll
    for (int m = 0; m < 4; ++m)
        #pragma unroll
        for (int n = 0; n < 4; ++n)
            acc[m][n] = (v4f)0.f;

    const int srow = wid * 32;             // this wave's 32 staged rows
    const int lrow = lane >> 3;            // 0..7
    const int lcol = (lane & 7) * 8;       // 0..56 (elements)

    for (int k0 = 0; k0 < kEnd; k0 += BK) {
        #pragma unroll
        for (int c = 0; c < 4; ++c) {
            int r = srow + c * 8;
            load_lds16(A + (size_t)(brow + r + lrow) * lda + k0 + lcol, As + r * BK);
            load_lds16(Bt + (size_t)(bcol + r + lrow) * ldb + k0 + lcol, Bs + r * BK);
        }
        __syncthreads();

        #pragma unroll
        for (int kk = 0; kk < BK; kk += 32) {
            const int fr = lane & 15;
            const int fk = kk + ((lane >> 4) << 3);
            v8s a[4], b[4];
            #pragma unroll
            for (int m = 0; m < 4; ++m)
                a[m] = *(const v8s*)(As + (wr * 64 + m * 16 + fr) * BK + fk);
            #pragma unroll
            for (int n = 0; n < 4; ++n)
                b[n] = *(const v8s*)(Bs + (wc * 64 + n * 16 + fr) * BK + fk);
            #pragma unroll
            for (int m = 0; m < 4; ++m)
                #pragma unroll
                for (int n = 0; n < 4; ++n)
                    acc[m][n] = __builtin_amdgcn_mfma_f32_16x16x32_bf16(a[m], b[n], acc[m][n], 0, 0, 0);
        }
        __syncthreads();
    }

    const int fr = lane & 15;
    const int fq = lane >> 4;

    if constexpr (MODE == 0) {
        ushort_t* C = (ushort_t*)Cv;
        #pragma unroll
        for (int n = 0; n < 4; ++n) {
            int gc = bcol + wc * 64 + n * 16 + fr;
            float bb = bias[gc];
            #pragma unroll
            for (int m = 0; m < 4; ++m) {
                int gr0 = brow + wr * 64 + m * 16 + fq * 4;
                #pragma unroll
                for (int j = 0; j < 4; ++j)
                    C[(size_t)(gr0 + j) * ldc + gc] = f2bf((acc[m][n][j] + bb) * scale);
            }
        }
    } else if constexpr (MODE == 1) {
        ushort_t* C = (ushort_t*)Cv;   // per-batch [1024][2048]
        #pragma unroll
        for (int n = 0; n < 4; ++n) {
            int gc = bcol + wc * 64 + n * 16 + fr;          // e index
            float bb = bias[gc];
            #pragma unroll
            for (int m = 0; m < 4; ++m) {
                int gr0 = brow + wr * 64 + m * 16 + fq * 4; // global row (b*2048+s)
                int bbatch = gr0 >> 11;
                int sl = gr0 & 2047;
                alignas(8) ushort_t tmp[4];
                #pragma unroll
                for (int j = 0; j < 4; ++j)
                    tmp[j] = f2bf(acc[m][n][j] + bb);
                *(v4s*)(C + (size_t)bbatch * (1024 * 2048) + (size_t)gc * 2048 + sl) =
                    *(const v4s*)tmp;
            }
        }
    } else {
        float* C = (float*)Cv + (size_t)bz * strideC;
        #pragma unroll
        for (int n = 0; n < 4; ++n) {
            int gc = bcol + wc * 64 + n * 16 + fr;
            #pragma unroll
            for (int m = 0; m < 4; ++m) {
                int gr0 = brow + wr * 64 + m * 16 + fq * 4;
                #pragma unroll
                for (int j = 0; j < 4; ++j)
                    C[(size_t)(gr0 + j) * ldc + gc] = acc[m][n][j] * scale;
            }
        }
    }
}

// ---------------------------------------------------------------------------
// causal row softmax; reads fp32 scores row, writes bf16 P in-place over the
// row start (row pitch stays 2048 fp32 = 4096 bf16). P[j]=0 for j>i.
__global__ __launch_bounds__(256) void softmax_causal(float* __restrict__ Sc) {
    int row = blockIdx.x;            // 0..8191  (b*2048 + i)
    int b = row >> 11, i = row & 2047;
    float* srow = Sc + ((size_t)b * 2048 + i) * 2048;
    int L = i + 1;
    __shared__ float vals[2048];
    __shared__ float red[8];
    int tid = threadIdx.x, lane = tid & 63, wid = tid >> 6;

    float mx = -3.0e38f;
    for (int j = tid; j < L; j += 256) {
        float v = srow[j];
        vals[j] = v;
        mx = fmaxf(mx, v);
    }
    #pragma unroll
    for (int o = 32; o; o >>= 1) mx = fmaxf(mx, __shfl_down(mx, o));
    if (lane == 0) red[wid] = mx;
    __syncthreads();
    mx = fmaxf(fmaxf(red[0], red[1]), fmaxf(red[2], red[3]));

    float sum = 0.f;
    for (int j = tid; j < L; j += 256) {
        float e = __expf(vals[j] - mx);
        vals[j] = e;
        sum += e;
    }
    #pragma unroll
    for (int o = 32; o; o >>= 1) sum += __shfl_down(sum, o);
    if (lane == 0) red[wid + 4] = sum;
    __syncthreads();
    float inv = 1.f / (red[4] + red[5] + red[6] + red[7]);

    ushort_t* prow = (ushort_t*)srow;
    for (int j = tid; j < 2048; j += 256) {
        float p = (j < L) ? vals[j] * inv : 0.f;
        prow[j] = f2bf(p);
    }
}

// ---------------------------------------------------------------------------
extern "C" void kernel_launch(void* const* d_in, const int* in_sizes, int n_in,
                              void* d_out, int out_size, void* d_ws, size_t ws_size,
                              hipStream_t stream) {
    const float* x  = (const float*)d_in[0];
    // d_in[1] = additive causal mask: structurally known, not read.
    const float* Wq = (const float*)d_in[2];
    const float* bq = (const float*)d_in[3];
    const float* Wk = (const float*)d_in[4];
    const float* bk = (const float*)d_in[5];
    const float* Wv = (const float*)d_in[6];
    const float* bv = (const float*)d_in[7];

    // workspace layout (bytes):
    //   xb  bf16 8192x1024            16.78 MB
    //   Wt  bf16 3 x 1024x1024         6.29 MB
    //   Qb  bf16 8192x1024            16.78 MB   (scaled by 1/32)
    //   Kb  bf16 8192x1024            16.78 MB
    //   Vt  bf16 4 x 1024x2048        16.78 MB
    //   Sc  fp32 4 x 2048x2048        67.11 MB   (P bf16 written in place)
    ushort_t* xb = (ushort_t*)d_ws;
    ushort_t* Wt = xb + (size_t)8192 * 1024;
    ushort_t* Qb = Wt + (size_t)3 * 1024 * 1024;
    ushort_t* Kb = Qb + (size_t)8192 * 1024;
    ushort_t* Vt = Kb + (size_t)8192 * 1024;
    float*    Sc = (float*)(Vt + (size_t)8192 * 1024);

    cvt_kernel<<<2048, 256, 0, stream>>>((const float4*)x, xb, 8192 * 1024 / 4);
    transpose_w<<<dim3(32, 32, 3), dim3(32, 8), 0, stream>>>(Wq, Wk, Wv, Wt);

    // Q = (x Wq + bq) / sqrt(D);  K = x Wk + bk
    gemm_bt<0><<<dim3(8, 64, 1), 256, 0, stream>>>(xb, 1024, 0, Wt, 1024, 0,
                                                   bq, Qb, 1024, 0, 1024, 0.03125f);
    gemm_bt<0><<<dim3(8, 64, 1), 256, 0, stream>>>(xb, 1024, 0, Wt + (size_t)1024 * 1024, 1024, 0,
                                                   bk, Kb, 1024, 0, 1024, 1.0f);
    // V^T (per-batch [e][s])
    gemm_bt<1><<<dim3(8, 64, 1), 256, 0, stream>>>(xb, 1024, 0, Wt + (size_t)2 * 1024 * 1024, 1024, 0,
                                                   bv, Vt, 2048, 0, 1024, 1.0f);
    // scores = Q K^T  (batched; upper-tri blocks skipped)
    gemm_bt<2><<<dim3(16, 16, 4), 256, 0, stream>>>(Qb, 1024, 2048LL * 1024,
                                                    Kb, 1024, 2048LL * 1024,
                                                    nullptr, Sc, 2048, 2048LL * 2048, 1024, 1.0f);
    softmax_causal<<<8192, 256, 0, stream>>>(Sc);
    // O = P V   (A = bf16 P with row pitch 4096 elems; K-loop limited per row-block)
    gemm_bt<3><<<dim3(8, 16, 4), 256, 0, stream>>>((const ushort_t*)Sc, 4096, 2048LL * 4096,
                                                   Vt, 2048, 2048LL * 1024,
                                                   nullptr, d_out, 1024, 2048LL * 1024, 2048, 1.0f);
    (void)in_sizes; (void)n_in; (void)out_size; (void)ws_size;
}

// Round 2
// 203.360 us; speedup vs baseline: 1.0990x; 1.0990x over previous
//
#include <hip/hip_runtime.h>
#include <hip/hip_bf16.h>
#include <math.h>

typedef short v8s __attribute__((ext_vector_type(8)));
typedef short v4s __attribute__((ext_vector_type(4)));
typedef float v4f __attribute__((ext_vector_type(4)));
typedef unsigned short ushort_t;

#define BM 128
#define BN 128
#define BK 64

__device__ __forceinline__ unsigned short f2bf(float f) {
    unsigned int u = __float_as_uint(f);
    u = (u + 0x7FFFu + ((u >> 16) & 1u)) >> 16;   // RNE
    return (unsigned short)u;
}

__device__ __forceinline__ void load_lds16(const void* g, void* l) {
    __builtin_amdgcn_global_load_lds((const __attribute__((address_space(1))) void*)g,
                                     (__attribute__((address_space(3))) void*)l,
                                     16, 0, 0);
}

// ---------------------------------------------------------------------------
__global__ __launch_bounds__(256) void cvt_kernel(const float4* __restrict__ in,
                                                  ushort_t* __restrict__ out, int n4) {
    int i = blockIdx.x * 256 + threadIdx.x;
    int stride = gridDim.x * 256;
    for (; i < n4; i += stride) {
        float4 v = in[i];
        v4s p;
        p[0] = (short)f2bf(v.x); p[1] = (short)f2bf(v.y);
        p[2] = (short)f2bf(v.z); p[3] = (short)f2bf(v.w);
        *(v4s*)(out + (size_t)i * 4) = p;
    }
}

// ---------------------------------------------------------------------------
// W (K x N, fp32, row-major) -> Wt (N x K, bf16); 3 weights stacked -> [3072][1024]
__global__ void transpose_w(const float* __restrict__ W0, const float* __restrict__ W1,
                            const float* __restrict__ W2, ushort_t* __restrict__ WtAll) {
    const float* W = (blockIdx.z == 0) ? W0 : (blockIdx.z == 1 ? W1 : W2);
    ushort_t* out = WtAll + (size_t)blockIdx.z * 1024 * 1024;
    __shared__ float tile[32][33];
    int n0 = blockIdx.x * 32, k0 = blockIdx.y * 32;
    int tx = threadIdx.x, ty = threadIdx.y;       // block (32, 8)
    #pragma unroll
    for (int i = 0; i < 32; i += 8)
        tile[ty + i][tx] = W[(size_t)(k0 + ty + i) * 1024 + n0 + tx];
    __syncthreads();
    #pragma unroll
    for (int i = 0; i < 32; i += 8)
        out[(size_t)(n0 + ty + i) * 1024 + k0 + tx] = f2bf(tile[tx][ty + i]);
}

// ---------------------------------------------------------------------------
// Merged QKV projection: C[8192x3072] = xb[8192x1024] * Wt[3072x1024]^T
// m97 structure (32 KB LDS, 2 barriers/iter) — 1536 blocks give co-residency.
// Epilogue routes by bx: bx<8 -> Qb (scaled), bx<16 -> Kb, else -> Vt (transposed).
__global__ __launch_bounds__(256)
void gemm_qkv(const ushort_t* __restrict__ A, const ushort_t* __restrict__ Bt,
              const float* __restrict__ bq, const float* __restrict__ bk,
              const float* __restrict__ bv,
              ushort_t* __restrict__ Qb, ushort_t* __restrict__ Kb,
              ushort_t* __restrict__ Vt)
{
    int flat = blockIdx.x;                    // 0..1535
    int swz = (flat & 7) * 192 + (flat >> 3); // XCD-aware bijective swizzle
    const int bx = swz % 24, by = swz / 24;

    const int tid = threadIdx.x;
    const int lane = tid & 63, wid = tid >> 6;
    const int wr = wid >> 1, wc = wid & 1;

    __shared__ ushort_t As[BM * BK];
    __shared__ ushort_t Bs[BN * BK];

    const int brow = by * BM, bcol = bx * BN;

    v4f acc[4][4];
    #pragma unroll
    for (int m = 0; m < 4; ++m)
        #pragma unroll
        for (int n = 0; n < 4; ++n)
            acc[m][n] = (v4f)0.f;

    const int srow = wid * 32;
    const int lrow = lane >> 3;
    const int lcol = (lane & 7) * 8;

    for (int k0 = 0; k0 < 1024; k0 += BK) {
        #pragma unroll
        for (int c = 0; c < 4; ++c) {
            int r = srow + c * 8;
            load_lds16(A + (size_t)(brow + r + lrow) * 1024 + k0 + lcol, As + r * BK);
            load_lds16(Bt + (size_t)(bcol + r + lrow) * 1024 + k0 + lcol, Bs + r * BK);
        }
        __syncthreads();
        #pragma unroll
        for (int kk = 0; kk < BK; kk += 32) {
            const int fr = lane & 15;
            const int fk = kk + ((lane >> 4) << 3);
            v8s a[4], b[4];
            #pragma unroll
            for (int m = 0; m < 4; ++m)
                a[m] = *(const v8s*)(As + (wr * 64 + m * 16 + fr) * BK + fk);
            #pragma unroll
            for (int n = 0; n < 4; ++n)
                b[n] = *(const v8s*)(Bs + (wc * 64 + n * 16 + fr) * BK + fk);
            #pragma unroll
            for (int m = 0; m < 4; ++m)
                #pragma unroll
                for (int n = 0; n < 4; ++n)
                    acc[m][n] = __builtin_amdgcn_mfma_f32_16x16x32_bf16(a[m], b[n], acc[m][n], 0, 0, 0);
        }
        __syncthreads();
    }

    const int fr = lane & 15;
    const int fq = lane >> 4;

    const float* bias; int cbase; float scale; int isV = 0;
    ushort_t* C;
    if (bx < 8)       { bias = bq; cbase = 0;    scale = 0.03125f; C = Qb; }
    else if (bx < 16) { bias = bk; cbase = 1024; scale = 1.0f;     C = Kb; }
    else              { bias = bv; cbase = 2048; scale = 1.0f;     C = nullptr; isV = 1; }

    if (!isV) {
        #pragma unroll
        for (int n = 0; n < 4; ++n) {
            int cg = bcol + wc * 64 + n * 16 + fr - cbase;
            float bb = bias[cg];
            #pragma unroll
            for (int m = 0; m < 4; ++m) {
                int gr0 = brow + wr * 64 + m * 16 + fq * 4;
                #pragma unroll
                for (int j = 0; j < 4; ++j)
                    C[(size_t)(gr0 + j) * 1024 + cg] = f2bf((acc[m][n][j] + bb) * scale);
            }
        }
    } else {
        #pragma unroll
        for (int n = 0; n < 4; ++n) {
            int e = bcol + wc * 64 + n * 16 + fr - 2048;     // 0..1023
            float bb = bias[e];
            #pragma unroll
            for (int m = 0; m < 4; ++m) {
                int gr0 = brow + wr * 64 + m * 16 + fq * 4;  // b*2048 + s
                int bbatch = gr0 >> 11;
                int sl = gr0 & 2047;
                alignas(8) ushort_t tmp[4];
                #pragma unroll
                for (int j = 0; j < 4; ++j)
                    tmp[j] = f2bf(acc[m][n][j] + bb);
                *(v4s*)(Vt + (size_t)bbatch * (1024 * 2048) + (size_t)e * 2048 + sl) =
                    *(const v4s*)tmp;
            }
        }
    }
}

// ---------------------------------------------------------------------------
// 2-phase double-buffered GEMM (T3 minimal recipe), fp32 out.
// MODE 2: causal QK^T — triangular-compacted grid (136 blocks/batch).
// MODE 3: PV — K limited to (by+1)*BM.
template <int MODE>
__global__ __launch_bounds__(256)
void gemm_db(const ushort_t* __restrict__ A, int lda, long long strideA,
             const ushort_t* __restrict__ Bt, int ldb, long long strideB,
             float* __restrict__ Cout, int ldc, long long strideC,
             int K, float scale)
{
    int bx, by;
    const int bz = blockIdx.z;
    if constexpr (MODE == 2) {
        int t = blockIdx.x;                  // 0..135
        t = (t & 7) * 17 + (t >> 3);         // XCD swizzle (136 = 8*17, bijective)
        int r = (int)((sqrtf(8.f * (float)t + 1.f) - 1.f) * 0.5f);
        while ((r + 1) * (r + 2) / 2 <= t) ++r;
        while (r * (r + 1) / 2 > t) --r;
        by = r; bx = t - r * (r + 1) / 2;    // row-major lower triangle
    } else {
        int f = blockIdx.y * 8 + blockIdx.x; // 8x16 = 128
        f = (f & 7) * 16 + (f >> 3);         // XCD swizzle (128 = 8*16)
        bx = f & 7; by = f >> 3;
    }

    const int tid = threadIdx.x;
    const int lane = tid & 63, wid = tid >> 6;
    const int wr = wid >> 1, wc = wid & 1;

    const ushort_t* Ab = A + (size_t)bz * strideA;
    const ushort_t* Bb = Bt + (size_t)bz * strideB;

    __shared__ ushort_t As[2][BM * BK];   // 32 KB
    __shared__ ushort_t Bs[2][BN * BK];   // 32 KB

    const int brow = by * BM, bcol = bx * BN;

    int kEnd = K;
    if constexpr (MODE == 3) { int lim = (by + 1) * BM; kEnd = lim < K ? lim : K; }
    const int nt = kEnd / BK;

    v4f acc[4][4];
    #pragma unroll
    for (int m = 0; m < 4; ++m)
        #pragma unroll
        for (int n = 0; n < 4; ++n)
            acc[m][n] = (v4f)0.f;

    const int srow = wid * 32;
    const int lrow = lane >> 3;
    const int lcol = (lane & 7) * 8;

    auto STAGE = [&](int buf, int k0) {
        #pragma unroll
        for (int c = 0; c < 4; ++c) {
            int r = srow + c * 8;
            load_lds16(Ab + (size_t)(brow + r + lrow) * lda + k0 + lcol, &As[buf][r * BK]);
            load_lds16(Bb + (size_t)(bcol + r + lrow) * ldb + k0 + lcol, &Bs[buf][r * BK]);
        }
    };

    STAGE(0, 0);
    __syncthreads();                      // drains vmcnt(0): buf0 resident

    for (int t = 0; t < nt; ++t) {
        const int cur = t & 1;
        if (t + 1 < nt) STAGE(cur ^ 1, (t + 1) * BK);   // async prefetch
        const ushort_t* Ac = As[cur];
        const ushort_t* Bc = Bs[cur];
        #pragma unroll
        for (int kk = 0; kk < BK; kk += 32) {
            const int fr = lane & 15;
            const int fk = kk + ((lane >> 4) << 3);
            v8s a[4], b[4];
            #pragma unroll
            for (int m = 0; m < 4; ++m)
                a[m] = *(const v8s*)(Ac + (wr * 64 + m * 16 + fr) * BK + fk);
            #pragma unroll
            for (int n = 0; n < 4; ++n)
                b[n] = *(const v8s*)(Bc + (wc * 64 + n * 16 + fr) * BK + fk);
            #pragma unroll
            for (int m = 0; m < 4; ++m)
                #pragma unroll
                for (int n = 0; n < 4; ++n)
                    acc[m][n] = __builtin_amdgcn_mfma_f32_16x16x32_bf16(a[m], b[n], acc[m][n], 0, 0, 0);
        }
        __syncthreads();                  // drains prefetch + gates buffer reuse
    }

    float* C = Cout + (size_t)bz * strideC;
    const int fr = lane & 15;
    const int fq = lane >> 4;
    #pragma unroll
    for (int n = 0; n < 4; ++n) {
        int gc = bcol + wc * 64 + n * 16 + fr;
        #pragma unroll
        for (int m = 0; m < 4; ++m) {
            int gr0 = brow + wr * 64 + m * 16 + fq * 4;
            #pragma unroll
            for (int j = 0; j < 4; ++j)
                C[(size_t)(gr0 + j) * ldc + gc] = acc[m][n][j] * scale;
        }
    }
}

// ---------------------------------------------------------------------------
// causal row softmax; fp32 scores row -> bf16 P in place (row pitch 4096 bf16).
// Writes only Lw = round-up-128(i+1) columns — PV never reads beyond.
__global__ __launch_bounds__(256) void softmax_causal(float* __restrict__ Sc) {
    int row = blockIdx.x;                // b*2048 + i
    int b = row >> 11, i = row & 2047;
    float* srow = Sc + ((size_t)b * 2048 + i) * 2048;
    const int L = i + 1;
    const int Lw = ((i >> 7) + 1) << 7;
    __shared__ float vals[2048];
    __shared__ float red[8];
    int tid = threadIdx.x, lane = tid & 63, wid = tid >> 6;

    float mx = -3.0e38f;
    const int L4 = L >> 2;
    for (int j = tid; j < L4; j += 256) {
        float4 v = ((const float4*)srow)[j];
        ((float4*)vals)[j] = v;
        mx = fmaxf(fmaxf(mx, fmaxf(v.x, v.y)), fmaxf(v.z, v.w));
    }
    {
        int j = (L4 << 2) + tid;
        if (j < L) { float v = srow[j]; vals[j] = v; mx = fmaxf(mx, v); }
    }
    #pragma unroll
    for (int o = 32; o; o >>= 1) mx = fmaxf(mx, __shfl_down(mx, o));
    if (lane == 0) red[wid] = mx;
    __syncthreads();
    mx = fmaxf(fmaxf(red[0], red[1]), fmaxf(red[2], red[3]));

    float sum = 0.f;
    for (int j = tid; j < L; j += 256) {
        float e = __expf(vals[j] - mx);
        vals[j] = e;
        sum += e;
    }
    #pragma unroll
    for (int o = 32; o; o >>= 1) sum += __shfl_down(sum, o);
    if (lane == 0) red[wid + 4] = sum;
    __syncthreads();
    float inv = 1.f / (red[4] + red[5] + red[6] + red[7]);

    ushort_t* prow = (ushort_t*)srow;
    for (int j4 = tid; j4 * 4 < Lw; j4 += 256) {
        int j = j4 * 4;
        float4 v = ((const float4*)vals)[j4];
        v4s p;
        p[0] = (short)f2bf((j     < L) ? v.x * inv : 0.f);
        p[1] = (short)f2bf((j + 1 < L) ? v.y * inv : 0.f);
        p[2] = (short)f2bf((j + 2 < L) ? v.z * inv : 0.f);
        p[3] = (short)f2bf((j + 3 < L) ? v.w * inv : 0.f);
        *(v4s*)(prow + j) = p;
    }
}

// ---------------------------------------------------------------------------
extern "C" void kernel_launch(void* const* d_in, const int* in_sizes, int n_in,
                              void* d_out, int out_size, void* d_ws, size_t ws_size,
                              hipStream_t stream) {
    const float* x  = (const float*)d_in[0];
    // d_in[1] = additive causal mask: structurally known, not read.
    const float* Wq = (const float*)d_in[2];
    const float* bq = (const float*)d_in[3];
    const float* Wk = (const float*)d_in[4];
    const float* bk = (const float*)d_in[5];
    const float* Wv = (const float*)d_in[6];
    const float* bv = (const float*)d_in[7];

    ushort_t* xb = (ushort_t*)d_ws;                        // 16.78 MB
    ushort_t* Wt = xb + (size_t)8192 * 1024;               //  6.29 MB (3x1024x1024)
    ushort_t* Qb = Wt + (size_t)3 * 1024 * 1024;           // 16.78 MB (scaled 1/32)
    ushort_t* Kb = Qb + (size_t)8192 * 1024;               // 16.78 MB
    ushort_t* Vt = Kb + (size_t)8192 * 1024;               // 16.78 MB (4x[1024][2048])
    float*    Sc = (float*)(Vt + (size_t)8192 * 1024);     // 67.11 MB

    cvt_kernel<<<2048, 256, 0, stream>>>((const float4*)x, xb, 8192 * 1024 / 4);
    transpose_w<<<dim3(32, 32, 3), dim3(32, 8), 0, stream>>>(Wq, Wk, Wv, Wt);

    // fused Q/K/V projection (N=3072)
    gemm_qkv<<<1536, 256, 0, stream>>>(xb, Wt, bq, bk, bv, Qb, Kb, Vt);

    // scores = Q K^T (causal, triangular grid, 2-phase dbuf)
    gemm_db<2><<<dim3(136, 1, 4), 256, 0, stream>>>(Qb, 1024, 2048LL * 1024,
                                                    Kb, 1024, 2048LL * 1024,
                                                    Sc, 2048, 2048LL * 2048, 1024, 1.0f);
    softmax_causal<<<8192, 256, 0, stream>>>(Sc);
    // O = P V (2-phase dbuf, per-row-block K limit)
    gemm_db<3><<<dim3(8, 16, 4), 256, 0, stream>>>((const ushort_t*)Sc, 4096, 2048LL * 4096,
                                                   Vt, 2048, 2048LL * 1024,
                                                   (float*)d_out, 1024, 2048LL * 1024, 2048, 1.0f);
    (void)in_sizes; (void)n_in; (void)out_size; (void)ws_size;
}